// Round 2
// baseline (4727.728 us; speedup 1.0000x reference)
//
#include <hip/hip_runtime.h>
#include <cstddef>
#include <cstdint>

// SigLIP block, fp32 baseline (round 2): de-risked workspace (113 MB) + LDS (<64KB).
// B=8 T=1024 D=1152 NH=16 F=4304 HD=72.
// Key fact: q.reshape(B,NH,T,HD) with no transpose => head h of batch b is the
// contiguous slab q[b, h*64:(h+1)*64, :] viewed as a contiguous [1024,72] matrix.

constexpr int kBatch = 8;
constexpr int kTok   = 1024;
constexpr int kDim   = 1152;
constexpr int kNH    = 16;
constexpr int kFF    = 4304;
constexpr int kHD    = 72;
constexpr int kNT    = kBatch * kTok;   // 8192 rows

// ---------------------------------------------------------------- LayerNorm
__global__ __launch_bounds__(256) void ln_kernel(const float* __restrict__ in,
                                                 const float* __restrict__ w,
                                                 const float* __restrict__ b,
                                                 float* __restrict__ out) {
  const int row = blockIdx.x;
  const float4* r4 = reinterpret_cast<const float4*>(in + (size_t)row * kDim);
  const float4* w4 = reinterpret_cast<const float4*>(w);
  const float4* b4 = reinterpret_cast<const float4*>(b);
  float4* o4 = reinterpret_cast<float4*>(out + (size_t)row * kDim);
  const int t = threadIdx.x;                 // 288 float4 per row: t and t+256 (t<32)
  float4 v0 = r4[t];
  float4 v1 = make_float4(0.f, 0.f, 0.f, 0.f);
  const bool second = (t < kDim / 4 - 256);  // t < 32
  if (second) v1 = r4[t + 256];
  float s  = v0.x + v0.y + v0.z + v0.w + v1.x + v1.y + v1.z + v1.w;
  float ss = v0.x * v0.x + v0.y * v0.y + v0.z * v0.z + v0.w * v0.w +
             v1.x * v1.x + v1.y * v1.y + v1.z * v1.z + v1.w * v1.w;
  #pragma unroll
  for (int m = 1; m <= 32; m <<= 1) {
    s  += __shfl_xor(s, m);
    ss += __shfl_xor(ss, m);
  }
  __shared__ float red[8];
  const int wave = t >> 6;
  if ((t & 63) == 0) { red[wave] = s; red[4 + wave] = ss; }
  __syncthreads();
  s  = red[0] + red[1] + red[2] + red[3];
  ss = red[4] + red[5] + red[6] + red[7];
  const float mean = s * (1.0f / kDim);
  const float var  = ss * (1.0f / kDim) - mean * mean;
  const float rs   = rsqrtf(var + 1e-5f);
  {
    float4 W = w4[t], Bv = b4[t], r;
    r.x = (v0.x - mean) * rs * W.x + Bv.x;
    r.y = (v0.y - mean) * rs * W.y + Bv.y;
    r.z = (v0.z - mean) * rs * W.z + Bv.z;
    r.w = (v0.w - mean) * rs * W.w + Bv.w;
    o4[t] = r;
  }
  if (second) {
    float4 W = w4[t + 256], Bv = b4[t + 256], r;
    r.x = (v1.x - mean) * rs * W.x + Bv.x;
    r.y = (v1.y - mean) * rs * W.y + Bv.y;
    r.z = (v1.z - mean) * rs * W.z + Bv.z;
    r.w = (v1.w - mean) * rs * W.w + Bv.w;
    o4[t + 256] = r;
  }
}

// ------------------------------------------------------------------- GELU
__device__ __forceinline__ float gelu_tanh(float x) {
  const float u = 0.7978845608028654f * (x + 0.044715f * x * x * x);
  return 0.5f * x * (1.0f + tanhf(u));
}

// --------------------------------------- GEMM: C = [res +] A * W^T [+ bias]
// A [N,K] row-major (lda=K), W rows stride ldw (>=K), C stride = M.
// 64x64 tile, BK=16, 256 threads, 4x4 micro-tile per thread. fp32 VALU.
template <int GELU, int RES, int BIAS>
__global__ __launch_bounds__(256) void gemm_tn(const float* __restrict__ A,
                                               const float* __restrict__ Wt,
                                               const float* __restrict__ bias,
                                               const float* __restrict__ res,
                                               float* __restrict__ C,
                                               int N, int M, int K, int ldw) {
  __shared__ float As[16][64];   // transposed: As[k][n]
  __shared__ float Bs[16][64];   // Bs[k][m]
  const int tid = threadIdx.x;
  const int bn = blockIdx.x, bm = blockIdx.y;
  const int tx = tid & 15, ty = tid >> 4;
  const int ldr = tid >> 2;            // 0..63 (tile row to load)
  const int ldk = (tid & 3) << 2;      // 0,4,8,12 (k offset)
  const float* Ap = A + (size_t)(bn * 64 + ldr) * K + ldk;
  int wr = bm * 64 + ldr;
  if (wr > M - 1) wr = M - 1;          // clamp (partial last tile)
  const float* Wp = Wt + (size_t)wr * ldw + ldk;
  float acc[4][4] = {};
  for (int k0 = 0; k0 < K; k0 += 16) {
    const float4 a = *reinterpret_cast<const float4*>(Ap + k0);
    const float4 w = *reinterpret_cast<const float4*>(Wp + k0);
    __syncthreads();
    As[ldk + 0][ldr] = a.x; As[ldk + 1][ldr] = a.y;
    As[ldk + 2][ldr] = a.z; As[ldk + 3][ldr] = a.w;
    Bs[ldk + 0][ldr] = w.x; Bs[ldk + 1][ldr] = w.y;
    Bs[ldk + 2][ldr] = w.z; Bs[ldk + 3][ldr] = w.w;
    __syncthreads();
    #pragma unroll
    for (int kk = 0; kk < 16; kk++) {
      const float4 av = *reinterpret_cast<const float4*>(&As[kk][ty << 2]);
      const float4 wv = *reinterpret_cast<const float4*>(&Bs[kk][tx << 2]);
      const float ar[4] = {av.x, av.y, av.z, av.w};
      const float wc[4] = {wv.x, wv.y, wv.z, wv.w};
      #pragma unroll
      for (int i = 0; i < 4; i++)
        #pragma unroll
        for (int j = 0; j < 4; j++)
          acc[i][j] = fmaf(ar[i], wc[j], acc[i][j]);
    }
  }
  const int mcol = (bm << 6) + (tx << 2);
  if (mcol >= M) return;               // M % 4 == 0 always -> exact guard
  float4 bv = make_float4(0.f, 0.f, 0.f, 0.f);
  if (BIAS) bv = *reinterpret_cast<const float4*>(bias + mcol);
  #pragma unroll
  for (int i = 0; i < 4; i++) {
    const int row = (bn << 6) + (ty << 2) + i;
    float4 v;
    v.x = acc[i][0] + bv.x; v.y = acc[i][1] + bv.y;
    v.z = acc[i][2] + bv.z; v.w = acc[i][3] + bv.w;
    if (GELU) {
      v.x = gelu_tanh(v.x); v.y = gelu_tanh(v.y);
      v.z = gelu_tanh(v.z); v.w = gelu_tanh(v.w);
    }
    const size_t off = (size_t)row * M + mcol;
    if (RES) {
      const float4 r4 = *reinterpret_cast<const float4*>(res + off);
      v.x += r4.x; v.y += r4.y; v.z += r4.z; v.w += r4.w;
    }
    *reinterpret_cast<float4*>(C + off) = v;
  }
}

// ------------------------------------------- out = x1 + broadcast(b2)
__global__ __launch_bounds__(256) void init_out_kernel(const float* __restrict__ x1,
                                                       const float* __restrict__ b2,
                                                       float* __restrict__ out) {
  const int i = blockIdx.x * 256 + threadIdx.x;      // float4 index, exact grid
  const float4 v = reinterpret_cast<const float4*>(x1)[i];
  const float4 b = reinterpret_cast<const float4*>(b2)[i % (kDim / 4)];
  float4 r;
  r.x = v.x + b.x; r.y = v.y + b.y; r.z = v.z + b.z; r.w = v.w + b.w;
  reinterpret_cast<float4*>(out)[i] = r;
}

// ------------------------------------------------- Flash attention (fp32)
// Per (b,h): Q,K,V are contiguous [1024,72] views at offset (b*T + h*64)*D.
// One WG = 64 query rows of one (b,h); online softmax over 16 K-tiles of 64.
// LDS 58.6 KB: Ps aliases Ks (K dead after S-compute; barrier between).
__global__ __launch_bounds__(256) void attn_kernel(const float* __restrict__ Qg,
                                                   const float* __restrict__ Kg,
                                                   const float* __restrict__ Vg,
                                                   float* __restrict__ Og) {
  __shared__ float Qs[64][73];     // stride 73: conflict-light reads
  __shared__ float KsPs[64][73];   // Ks during S-compute; Ps afterwards
  __shared__ float Vs[64][80];     // stride 80: float4 rows, cols 72..79 zeroed
  __shared__ float mrow[64], lrow[64], arow[64];
  const int tid = threadIdx.x;
  const int qt = blockIdx.x, hh = blockIdx.y, bb = blockIdx.z;
  const size_t base = ((size_t)bb * kTok + hh * 64) * kDim;  // head slab start
  const float* Qb = Qg + base + (size_t)qt * 64 * kHD;
  const float* Kb = Kg + base;
  const float* Vb = Vg + base;
  // Load Q tile 64x72 (coalesced float2)
  for (int i = tid; i < 64 * 36; i += 256) {
    const int r = i / 36, c2 = (i % 36) * 2;
    const float2 qv = *reinterpret_cast<const float2*>(Qb + r * kHD + c2);
    Qs[r][c2] = qv.x; Qs[r][c2 + 1] = qv.y;
  }
  if (tid < 64) { mrow[tid] = -3.0e38f; lrow[tid] = 0.f; }
  const int tx = tid & 15, ty = tid >> 4;     // S phase: rows ty*4+i, cols tx*4+j
  const int prow = tid & 63, pcg = tid >> 6;  // PV phase: row prow, cols pcg*20..
  float Oa[20];
  #pragma unroll
  for (int j = 0; j < 20; j++) Oa[j] = 0.f;
  const float scale = 0.11785113019775793f;  // 72^-0.5

  for (int kt = 0; kt < 16; kt++) {
    __syncthreads();   // prev PV (reads KsPs,Vs,arow) done before overwrite
    const float* Kp = Kb + (size_t)kt * 64 * kHD;
    const float* Vp = Vb + (size_t)kt * 64 * kHD;
    for (int i = tid; i < 64 * 36; i += 256) {
      const int r = i / 36, c2 = (i % 36) * 2;
      const float2 kv = *reinterpret_cast<const float2*>(Kp + r * kHD + c2);
      KsPs[r][c2] = kv.x; KsPs[r][c2 + 1] = kv.y;
      const float2 vv = *reinterpret_cast<const float2*>(Vp + r * kHD + c2);
      Vs[r][c2] = vv.x; Vs[r][c2 + 1] = vv.y;
    }
    { // zero V pad columns 72..79
      const int r = tid >> 2, c = 72 + ((tid & 3) << 1);
      Vs[r][c] = 0.f; Vs[r][c + 1] = 0.f;
    }
    __syncthreads();

    // ---- S = Q K^T (4x4 per thread over 72-d inner product)
    float sacc[4][4] = {};
    #pragma unroll 8
    for (int e = 0; e < kHD; e++) {
      float qv[4], kv[4];
      #pragma unroll
      for (int i = 0; i < 4; i++) qv[i] = Qs[(ty << 2) + i][e];
      #pragma unroll
      for (int j = 0; j < 4; j++) kv[j] = KsPs[(tx << 2) + j][e];
      #pragma unroll
      for (int i = 0; i < 4; i++)
        #pragma unroll
        for (int j = 0; j < 4; j++)
          sacc[i][j] = fmaf(qv[i], kv[j], sacc[i][j]);
    }
    __syncthreads();   // all K reads done before P overwrites the buffer

    // ---- online softmax (row reduce across the 16 tx lanes: same wave)
    #pragma unroll
    for (int i = 0; i < 4; i++) {
      float mx = fmaxf(fmaxf(sacc[i][0], sacc[i][1]),
                       fmaxf(sacc[i][2], sacc[i][3]));
      #pragma unroll
      for (int m = 1; m <= 8; m <<= 1) mx = fmaxf(mx, __shfl_xor(mx, m));
      const float mxs  = mx * scale;
      const float mold = mrow[(ty << 2) + i];   // in-wave lockstep: read-before-write
      const float mnew = fmaxf(mold, mxs);
      float pr[4], sum = 0.f;
      #pragma unroll
      for (int j = 0; j < 4; j++) {
        pr[j] = __expf(fmaf(sacc[i][j], scale, -mnew));
        sum += pr[j];
      }
      #pragma unroll
      for (int m = 1; m <= 8; m <<= 1) sum += __shfl_xor(sum, m);
      if (tx == 0) {
        const float al = __expf(mold - mnew);
        arow[(ty << 2) + i] = al;
        mrow[(ty << 2) + i] = mnew;
        lrow[(ty << 2) + i] = lrow[(ty << 2) + i] * al + sum;
      }
      #pragma unroll
      for (int j = 0; j < 4; j++) KsPs[(ty << 2) + i][(tx << 2) + j] = pr[j];
    }
    __syncthreads();

    // ---- O = O*alpha + P V  (row prow, 20 cols per thread; V reads broadcast)
    const float al = arow[prow];
    #pragma unroll
    for (int j = 0; j < 20; j++) Oa[j] *= al;
    #pragma unroll 4
    for (int s = 0; s < 64; s++) {
      const float p = KsPs[prow][s];
      const float4* vr = reinterpret_cast<const float4*>(&Vs[s][pcg * 20]);
      const float4 v0 = vr[0], v1 = vr[1], v2 = vr[2], v3 = vr[3], v4 = vr[4];
      Oa[0]  = fmaf(p, v0.x, Oa[0]);  Oa[1]  = fmaf(p, v0.y, Oa[1]);
      Oa[2]  = fmaf(p, v0.z, Oa[2]);  Oa[3]  = fmaf(p, v0.w, Oa[3]);
      Oa[4]  = fmaf(p, v1.x, Oa[4]);  Oa[5]  = fmaf(p, v1.y, Oa[5]);
      Oa[6]  = fmaf(p, v1.z, Oa[6]);  Oa[7]  = fmaf(p, v1.w, Oa[7]);
      Oa[8]  = fmaf(p, v2.x, Oa[8]);  Oa[9]  = fmaf(p, v2.y, Oa[9]);
      Oa[10] = fmaf(p, v2.z, Oa[10]); Oa[11] = fmaf(p, v2.w, Oa[11]);
      Oa[12] = fmaf(p, v3.x, Oa[12]); Oa[13] = fmaf(p, v3.y, Oa[13]);
      Oa[14] = fmaf(p, v3.z, Oa[14]); Oa[15] = fmaf(p, v3.w, Oa[15]);
      Oa[16] = fmaf(p, v4.x, Oa[16]); Oa[17] = fmaf(p, v4.y, Oa[17]);
      Oa[18] = fmaf(p, v4.z, Oa[18]); Oa[19] = fmaf(p, v4.w, Oa[19]);
    }
  }
  // ---- epilogue: normalize and scatter to o[b, s, h*72+e]
  const float inv = 1.0f / lrow[prow];
  const size_t obase =
      ((size_t)bb * kTok + (size_t)qt * 64 + prow) * kDim + hh * kHD + pcg * 20;
  #pragma unroll
  for (int j = 0; j < 20; j++) {
    if (pcg * 20 + j < kHD) Og[obase + j] = Oa[j] * inv;
  }
}

// ----------------------------------------------------------------- launch
extern "C" void kernel_launch(void* const* d_in, const int* in_sizes, int n_in,
                              void* d_out, int out_size, void* d_ws, size_t ws_size,
                              hipStream_t stream) {
  const float* x     = (const float*)d_in[0];
  const float* ln1w  = (const float*)d_in[1];
  const float* ln1b  = (const float*)d_in[2];
  const float* wq    = (const float*)d_in[3];
  const float* bq    = (const float*)d_in[4];
  const float* wk    = (const float*)d_in[5];
  const float* bk    = (const float*)d_in[6];
  const float* wv    = (const float*)d_in[7];
  const float* bv    = (const float*)d_in[8];
  const float* wo    = (const float*)d_in[9];
  const float* bo    = (const float*)d_in[10];
  const float* ln2w  = (const float*)d_in[11];
  const float* ln2b  = (const float*)d_in[12];
  const float* w1    = (const float*)d_in[13];
  const float* b1    = (const float*)d_in[14];
  const float* w2    = (const float*)d_in[15];
  const float* b2    = (const float*)d_in[16];
  float* out = (float*)d_out;

  // workspace: 3 x [8192,1152] fp32 slots = 113.2 MB total.
  //  slot0: h (LN1 out)  -> o (attn out)        -> f-chunk buffer
  //  slot1: k            -> x1 (residual 1)
  //  slot2: v            -> h2 (LN2 out)
  //  q lives in d_out (dead before out-init).
  float* ws = (float*)d_ws;
  const size_t nD = (size_t)kNT * kDim;
  float* s0 = ws;
  float* s1 = ws + nD;
  float* s2 = ws + 2 * nD;
  float* q  = out;          // d_out doubles as q until out-init
  float* h  = s0;
  float* k  = s1;
  float* v  = s2;
  float* o  = s0;
  float* x1 = s1;
  float* h2 = s2;
  float* fb = s0;           // f-chunk buffer [8192 x <=1088]

  const dim3 blk(256);
  const dim3 gq(kNT / 64, kDim / 64);          // (128, 18)
  const dim3 ga(kTok / 64, kNH, kBatch);       // (16, 16, 8)

  ln_kernel<<<kNT, blk, 0, stream>>>(x, ln1w, ln1b, h);
  gemm_tn<0, 0, 1><<<gq, blk, 0, stream>>>(h, wq, bq, nullptr, q, kNT, kDim, kDim, kDim);
  gemm_tn<0, 0, 1><<<gq, blk, 0, stream>>>(h, wk, bk, nullptr, k, kNT, kDim, kDim, kDim);
  gemm_tn<0, 0, 1><<<gq, blk, 0, stream>>>(h, wv, bv, nullptr, v, kNT, kDim, kDim, kDim);
  attn_kernel<<<ga, blk, 0, stream>>>(q, k, v, o);
  gemm_tn<0, 1, 1><<<gq, blk, 0, stream>>>(o, wo, bo, x, x1, kNT, kDim, kDim, kDim);
  ln_kernel<<<kNT, blk, 0, stream>>>(x1, ln2w, ln2b, h2);
  init_out_kernel<<<nD / 4 / 256, blk, 0, stream>>>(x1, b2, out);   // out = x1 + b2

  // MLP: F chunked so hidden activations never exceed one ws slot.
  const int chunks[4] = {1088, 1088, 1088, 1040};
  int j0 = 0;
  for (int c = 0; c < 4; c++) {
    const int FC = chunks[c];
    const dim3 g1(kNT / 64, (FC + 63) / 64);
    // fb = gelu(h2 @ w1[j0:j0+FC,:]^T + b1[j0:])
    gemm_tn<1, 0, 1><<<g1, blk, 0, stream>>>(h2, w1 + (size_t)j0 * kDim, b1 + j0,
                                             nullptr, fb, kNT, FC, kDim, kDim);
    // out += fb @ w2[:, j0:j0+FC]^T   (w2 row stride = kFF)
    gemm_tn<0, 1, 0><<<gq, blk, 0, stream>>>(fb, w2 + j0, nullptr, out, out,
                                             kNT, kDim, FC, kFF);
    j0 += FC;
  }
}

// Round 4
// 982.293 us; speedup vs baseline: 4.8130x; 4.8130x over previous
//
#include <hip/hip_runtime.h>
#include <cstddef>
#include <cstdint>

// SigLIP block, bf16-MFMA round 4 (R3 + fixed attention-output scatter).
// B=8 T=1024 D=1152 NH=16 F=4304 HD=72.
// Head slab fact: q.reshape(B,NH,T,HD) no-transpose => head h of batch b is
// token rows [h*64,(h+1)*64); within-head position s = (t%64)*16 + d/72,
// e = d%72. Attention OUTPUT is transposed back: O[b][h][s][e] ->
// out[(b*1024+s)*1152 + h*72 + e]  (this was R3's bug: it used the input-slab
// layout (b*1024+h*64)*1152 + s*72 + e).

constexpr int kB = 8, kT = 1024, kD = 1152, kNH = 16, kF = 4304, kHD = 72;
constexpr int kNT = kB * kT;     // 8192
constexpr int kFP = 4352;        // padded F (34*128)
constexpr int kEP = 96;          // padded head-dim for Q/K (3*32)
constexpr int kEV = 80;          // padded head-dim rows for V^T (5*16)
constexpr int kFC = 2176;        // MLP chunk (kFP/2 = 17*128)

typedef short bf16x8 __attribute__((ext_vector_type(8)));
typedef float f32x4 __attribute__((ext_vector_type(4)));

__device__ __forceinline__ ushort f2bf(float f) {
  union { float f; uint u; } a; a.f = f;
  const uint r = a.u + 0x7FFFu + ((a.u >> 16) & 1u);   // RNE (finite inputs)
  return (ushort)(r >> 16);
}
__device__ __forceinline__ float gelu_tanh(float x) {
  const float u = 0.7978845608028654f * (x + 0.044715f * x * x * x);
  return 0.5f * x * (1.0f + tanhf(u));
}
#define GLL16(g, s) __builtin_amdgcn_global_load_lds( \
    (const __attribute__((address_space(1))) void*)(g), \
    (__attribute__((address_space(3))) void*)(s), 16, 0, 0)

// ---------------------------------------------------------------- LayerNorm
__global__ __launch_bounds__(256) void ln_kernel(const float* __restrict__ in,
                                                 const float* __restrict__ w,
                                                 const float* __restrict__ b,
                                                 ushort* __restrict__ out) {
  const int row = blockIdx.x;
  const float4* r4 = reinterpret_cast<const float4*>(in + (size_t)row * kD);
  const float4* w4 = reinterpret_cast<const float4*>(w);
  const float4* b4 = reinterpret_cast<const float4*>(b);
  const int t = threadIdx.x;                 // 288 float4/row: t and t+256 (t<32)
  float4 v0 = r4[t];
  float4 v1 = make_float4(0.f, 0.f, 0.f, 0.f);
  const bool second = (t < kD / 4 - 256);
  if (second) v1 = r4[t + 256];
  float s  = v0.x + v0.y + v0.z + v0.w + v1.x + v1.y + v1.z + v1.w;
  float ss = v0.x * v0.x + v0.y * v0.y + v0.z * v0.z + v0.w * v0.w +
             v1.x * v1.x + v1.y * v1.y + v1.z * v1.z + v1.w * v1.w;
  #pragma unroll
  for (int m = 1; m <= 32; m <<= 1) { s += __shfl_xor(s, m); ss += __shfl_xor(ss, m); }
  __shared__ float red[8];
  const int wave = t >> 6;
  if ((t & 63) == 0) { red[wave] = s; red[4 + wave] = ss; }
  __syncthreads();
  s  = red[0] + red[1] + red[2] + red[3];
  ss = red[4] + red[5] + red[6] + red[7];
  const float mean = s * (1.0f / kD);
  const float var  = ss * (1.0f / kD) - mean * mean;
  const float rs   = rsqrtf(var + 1e-5f);
  ushort4* o4 = reinterpret_cast<ushort4*>(out + (size_t)row * kD);
  {
    float4 W = w4[t], Bv = b4[t];
    ushort4 r;
    r.x = f2bf((v0.x - mean) * rs * W.x + Bv.x);
    r.y = f2bf((v0.y - mean) * rs * W.y + Bv.y);
    r.z = f2bf((v0.z - mean) * rs * W.z + Bv.z);
    r.w = f2bf((v0.w - mean) * rs * W.w + Bv.w);
    o4[t] = r;
  }
  if (second) {
    float4 W = w4[t + 256], Bv = b4[t + 256];
    ushort4 r;
    r.x = f2bf((v1.x - mean) * rs * W.x + Bv.x);
    r.y = f2bf((v1.y - mean) * rs * W.y + Bv.y);
    r.z = f2bf((v1.z - mean) * rs * W.z + Bv.z);
    r.w = f2bf((v1.w - mean) * rs * W.w + Bv.w);
    o4[t + 256] = r;
  }
}

// ---------------------------------------------------------------- converters
__global__ __launch_bounds__(256) void cvt4_kernel(const float* __restrict__ src,
                                                   ushort* __restrict__ dst, int n4) {
  const int i = blockIdx.x * 256 + threadIdx.x;
  if (i < n4) {
    const float4 v = reinterpret_cast<const float4*>(src)[i];
    ushort4 r = { f2bf(v.x), f2bf(v.y), f2bf(v.z), f2bf(v.w) };
    reinterpret_cast<ushort4*>(dst)[i] = r;
  }
}
// w2 [1152][4304] -> w2b [1152][4352], pad cols MUST be zero.
__global__ __launch_bounds__(256) void cvtw2_kernel(const float* __restrict__ src,
                                                    ushort* __restrict__ dst) {
  const int i = blockIdx.x * 256 + threadIdx.x;
  if (i >= kD * (kFP / 4)) return;
  const int r = i / (kFP / 4), c4 = i % (kFP / 4);
  const int c = c4 * 4;
  ushort4 o;
  if (c < kF) {
    const float4 v = *reinterpret_cast<const float4*>(src + (size_t)r * kF + c);
    o = { f2bf(v.x), f2bf(v.y), f2bf(v.z), f2bf(v.w) };
  } else o = { 0, 0, 0, 0 };
  reinterpret_cast<ushort4*>(dst + (size_t)r * kFP)[c4] = o;
}
__global__ __launch_bounds__(256) void b1pad_kernel(const float* __restrict__ src,
                                                    float* __restrict__ dst) {
  const int i = blockIdx.x * 256 + threadIdx.x;
  if (i < kFP) dst[i] = (i < kF) ? src[i] : 0.f;
}
// zero the K e-pad cols [72,96) and V^T e-pad rows [72,80)
__global__ __launch_bounds__(256) void zfill_kernel(ushort* __restrict__ kp,
                                                    ushort* __restrict__ vt) {
  const int i = blockIdx.x * 256 + threadIdx.x;
  const int nk = 131072 * 24;
  if (i < nk) {
    const int row = i / 24, c = 72 + i % 24;
    kp[(size_t)row * kEP + c] = 0;
  } else {
    const int j = i - nk;
    if (j < 131072 * 8) {
      const int bh = j >> 13, rem = j & 8191;
      const int e = 72 + (rem >> 10), s = rem & 1023;
      vt[((size_t)bh * kEV + e) * 1024 + s] = 0;
    }
  }
}

// ------------------------------------------------------------- MFMA GEMM
// C = [res +] [gelu] [scale*] (A @ W^T + bias).  A [N][K] bf16, W [M-rows][ldw] bf16.
// 128x128 tile, BK=32, 4 waves (2x2), 4x4 16x16x32 frags/wave. All dims exact.
// MODE: 0 = f32 [N][M]; 1 = bf16 [N][M]; 2 = bf16 q/k-padded [bh][1024][96];
//       3 = bf16 vT [bh][80][1024].
template <int MODE, int GELU_, int BIAS_, int RES_, int SCALE_>
__global__ __launch_bounds__(256) void gemm_mfma(
    const ushort* __restrict__ A, const ushort* __restrict__ W,
    const float* __restrict__ bias, const float* __restrict__ res,
    void* __restrict__ Cout, int M, int K, int ldw) {
  __shared__ __align__(16) ushort As[128 * 32];
  __shared__ __align__(16) ushort Bs[128 * 32];
  const int tid = threadIdx.x;
  const int l = tid & 63, w = tid >> 6;
  const int lr = l & 15, lg = l >> 4;
  const int wm = w >> 1, wn = w & 1;
  const int bn = blockIdx.x, bm = blockIdx.y;
  f32x4 acc[4][4] = {};
  const int srow = 32 * w + (l >> 2);       // staging row (+0 / +16 per issue)
  const int scol = (l & 3) * 8;             // staging k-offset (elements)
  const ushort* Ag = A + (size_t)(bn * 128 + srow) * K + scol;
  const ushort* Wg = W + (size_t)(bm * 128 + srow) * ldw + scol;
  for (int k0 = 0; k0 < K; k0 += 32) {
    __syncthreads();
    #pragma unroll
    for (int i = 0; i < 2; i++) {
      GLL16(Ag + (size_t)(16 * i) * K + k0, &As[(32 * w + 16 * i) * 32]);
      GLL16(Wg + (size_t)(16 * i) * ldw + k0, &Bs[(32 * w + 16 * i) * 32]);
    }
    __syncthreads();
    bf16x8 af[4], bf[4];
    #pragma unroll
    for (int mf = 0; mf < 4; mf++)
      af[mf] = *(const bf16x8*)&As[(wm * 64 + mf * 16 + lr) * 32 + lg * 8];
    #pragma unroll
    for (int nf = 0; nf < 4; nf++)
      bf[nf] = *(const bf16x8*)&Bs[(wn * 64 + nf * 16 + lr) * 32 + lg * 8];
    #pragma unroll
    for (int mf = 0; mf < 4; mf++)
      #pragma unroll
      for (int nf = 0; nf < 4; nf++)
        acc[mf][nf] = __builtin_amdgcn_mfma_f32_16x16x32_bf16(af[mf], bf[nf], acc[mf][nf], 0, 0, 0);
  }
  // epilogue: C layout col = lane&15, row = (lane>>4)*4 + j
  #pragma unroll
  for (int mf = 0; mf < 4; mf++) {
    #pragma unroll
    for (int nf = 0; nf < 4; nf++) {
      const int c = bm * 128 + wn * 64 + nf * 16 + lr;
      const float bv = BIAS_ ? bias[c] : 0.f;
      #pragma unroll
      for (int j = 0; j < 4; j++) {
        const int r = bn * 128 + wm * 64 + mf * 16 + lg * 4 + j;
        float v = acc[mf][nf][j] + bv;
        if (SCALE_) v *= 0.11785113019775793f;      // 72^-0.5 folded into q
        if (GELU_) v = gelu_tanh(v);
        if (RES_) v += res[(size_t)r * M + c];
        if (MODE == 0) {
          ((float*)Cout)[(size_t)r * M + c] = v;
        } else if (MODE == 1) {
          ((ushort*)Cout)[(size_t)r * M + c] = f2bf(v);
        } else {
          const int b = r >> 10, t = r & 1023;
          const int h = t >> 6, u = t & 63;
          const int jj = c / 72, e = c - jj * 72;
          const int s = u * 16 + jj;
          const int bh = b * 16 + h;
          size_t dst;
          if (MODE == 2) dst = ((size_t)bh * 1024 + s) * kEP + e;
          else           dst = ((size_t)bh * kEV + e) * 1024 + s;
          ((ushort*)Cout)[dst] = f2bf(v);
        }
      }
    }
  }
}

// ------------------------------------------------------- MFMA flash attention
// qp/kp: [bh][1024][96] bf16 (q prescaled; kp e-pad zeroed). vt: [bh][80][1024]
// (rows 72..79 zeroed, XOR-swizzle staged). ob: natural [8192][1152] bf16,
// written TRANSPOSED back: O[bh][s][e] -> ob[(b*1024+s)*1152 + h*72 + e].
// Block = 4 waves; wave = 64 q-rows; 16 K-tiles of 64; online softmax in regs.
__global__ __launch_bounds__(256, 2) void attn_kernel(
    const ushort* __restrict__ qp, const ushort* __restrict__ kp,
    const ushort* __restrict__ vt, ushort* __restrict__ ob) {
  __shared__ __align__(16) ushort Kt[64 * 96];      // 12288 B
  __shared__ __align__(16) ushort Vt[80 * 64];      // 10240 B (swizzled)
  __shared__ __align__(16) ushort Ps[4][64 * 72];   // 36864 B (per-wave)
  const int tid = threadIdx.x, l = tid & 63, w = tid >> 6;
  const int lr = l & 15, lg = l >> 4;
  const int qb = blockIdx.x, hh = blockIdx.y, bb = blockIdx.z;
  const int bh = bb * 16 + hh;
  const int s0 = qb * 256 + w * 64;
  // Q fragments, kept in registers (12 x bf16x8)
  bf16x8 qf[4][3];
  const ushort* qbase = qp + (size_t)bh * 1024 * kEP;
  #pragma unroll
  for (int mf = 0; mf < 4; mf++)
    #pragma unroll
    for (int ks = 0; ks < 3; ks++)
      qf[mf][ks] = *(const bf16x8*)(qbase + (size_t)(s0 + mf * 16 + lr) * kEP + ks * 32 + lg * 8);
  float mstate[16], lstate[16];
  #pragma unroll
  for (int i = 0; i < 16; i++) { mstate[i] = -1e30f; lstate[i] = 0.f; }
  f32x4 oacc[4][5] = {};
  const ushort* ktile0 = kp + (size_t)bh * 1024 * kEP;
  const ushort* vbase  = vt + (size_t)bh * kEV * 1024;
  ushort* myPs = &Ps[w][0];

  for (int kt = 0; kt < 16; kt++) {
    __syncthreads();                       // prior tile's Kt/Vt reads done
    {  // K tile: contiguous 64x96 bf16 = 12KB, 12 linear issues (3/wave)
      const ushort* kg = ktile0 + (size_t)kt * 64 * kEP;
      #pragma unroll
      for (int i = 0; i < 3; i++) {
        const int is = w * 3 + i;
        GLL16(kg + is * 512 + l * 8, &Kt[is * 512]);
      }
    }
    {  // V^T tile: 80 rows x 128B, row-stride 2048B, XOR-swizzled source
      #pragma unroll
      for (int i = 0; i < 3; i++) {
        const int is = w + i * 4;
        if (is < 10) {
          const int e = is * 8 + (l >> 3);
          const int cg = (l & 7) ^ (e & 7);
          GLL16(vbase + (size_t)e * 1024 + kt * 64 + cg * 8, &Vt[is * 512]);
        }
      }
    }
    __syncthreads();
    // ---- S = Q K^T
    f32x4 sacc[4][4];
    #pragma unroll
    for (int mf = 0; mf < 4; mf++)
      #pragma unroll
      for (int nf = 0; nf < 4; nf++)
        sacc[mf][nf] = (f32x4){0.f, 0.f, 0.f, 0.f};
    #pragma unroll
    for (int ks = 0; ks < 3; ks++) {
      bf16x8 kf[4];
      #pragma unroll
      for (int nf = 0; nf < 4; nf++)
        kf[nf] = *(const bf16x8*)&Kt[(nf * 16 + lr) * 96 + ks * 32 + lg * 8];
      #pragma unroll
      for (int mf = 0; mf < 4; mf++)
        #pragma unroll
        for (int nf = 0; nf < 4; nf++)
          sacc[mf][nf] = __builtin_amdgcn_mfma_f32_16x16x32_bf16(qf[mf][ks], kf[nf], sacc[mf][nf], 0, 0, 0);
    }
    // ---- online softmax (row = lg*4+j per mf; reduce across the 16 lr lanes)
    #pragma unroll
    for (int mf = 0; mf < 4; mf++) {
      float alpha[4];
      #pragma unroll
      for (int j = 0; j < 4; j++) {
        float v = fmaxf(fmaxf(sacc[mf][0][j], sacc[mf][1][j]),
                        fmaxf(sacc[mf][2][j], sacc[mf][3][j]));
        v = fmaxf(v, __shfl_xor(v, 1));
        v = fmaxf(v, __shfl_xor(v, 2));
        v = fmaxf(v, __shfl_xor(v, 4));
        v = fmaxf(v, __shfl_xor(v, 8));
        const int si = mf * 4 + j;
        const float mo = mstate[si];
        const float mn = fmaxf(mo, v);
        float sum = 0.f;
        #pragma unroll
        for (int nf = 0; nf < 4; nf++) {
          const float p = __expf(sacc[mf][nf][j] - mn);
          sacc[mf][nf][j] = p;
          sum += p;
        }
        sum += __shfl_xor(sum, 1);
        sum += __shfl_xor(sum, 2);
        sum += __shfl_xor(sum, 4);
        sum += __shfl_xor(sum, 8);
        alpha[j] = __expf(mo - mn);
        lstate[si] = lstate[si] * alpha[j] + sum;
        mstate[si] = mn;
      }
      #pragma unroll
      for (int nf = 0; nf < 5; nf++)
        #pragma unroll
        for (int j = 0; j < 4; j++)
          oacc[mf][nf][j] *= alpha[j];
      #pragma unroll
      for (int nf = 0; nf < 4; nf++)
        #pragma unroll
        for (int j = 0; j < 4; j++)
          myPs[(mf * 16 + lg * 4 + j) * 72 + nf * 16 + lr] = f2bf(sacc[mf][nf][j]);
    }
    // ---- O += P V
    #pragma unroll
    for (int mf = 0; mf < 4; mf++) {
      bf16x8 pa0 = *(const bf16x8*)&myPs[(mf * 16 + lr) * 72 + lg * 8];
      bf16x8 pa1 = *(const bf16x8*)&myPs[(mf * 16 + lr) * 72 + 32 + lg * 8];
      #pragma unroll
      for (int nf = 0; nf < 5; nf++) {
        const int e = nf * 16 + lr;
        const int sw = e & 7;
        bf16x8 vb0 = *(const bf16x8*)&Vt[e * 64 + ((0 + lg) ^ sw) * 8];
        bf16x8 vb1 = *(const bf16x8*)&Vt[e * 64 + ((4 + lg) ^ sw) * 8];
        oacc[mf][nf] = __builtin_amdgcn_mfma_f32_16x16x32_bf16(pa0, vb0, oacc[mf][nf], 0, 0, 0);
        oacc[mf][nf] = __builtin_amdgcn_mfma_f32_16x16x32_bf16(pa1, vb1, oacc[mf][nf], 0, 0, 0);
      }
    }
  }
  // ---- epilogue: O /= l; scatter TRANSPOSED: ob[(b*1024+s)*1152 + h*72 + e]
  float linv[16];
  #pragma unroll
  for (int i = 0; i < 16; i++) linv[i] = 1.f / lstate[i];
  #pragma unroll
  for (int mf = 0; mf < 4; mf++)
    #pragma unroll
    for (int nf = 0; nf < 5; nf++) {
      const int e = nf * 16 + lr;
      if (e < 72) {
        #pragma unroll
        for (int j = 0; j < 4; j++) {
          const int s = s0 + mf * 16 + lg * 4 + j;
          ob[((size_t)bb * 1024 + s) * kD + hh * kHD + e] =
              f2bf(oacc[mf][nf][j] * linv[mf * 4 + j]);
        }
      }
    }
}

// ----------------------------------------------------------------- launch
extern "C" void kernel_launch(void* const* d_in, const int* in_sizes, int n_in,
                              void* d_out, int out_size, void* d_ws, size_t ws_size,
                              hipStream_t stream) {
  const float* x    = (const float*)d_in[0];
  const float* ln1w = (const float*)d_in[1];
  const float* ln1b = (const float*)d_in[2];
  const float* wq   = (const float*)d_in[3];
  const float* bq   = (const float*)d_in[4];
  const float* wk   = (const float*)d_in[5];
  const float* bk   = (const float*)d_in[6];
  const float* wv   = (const float*)d_in[7];
  const float* bv   = (const float*)d_in[8];
  const float* wo   = (const float*)d_in[9];
  const float* bo   = (const float*)d_in[10];
  const float* ln2w = (const float*)d_in[11];
  const float* ln2b = (const float*)d_in[12];
  const float* w1   = (const float*)d_in[13];
  const float* b1   = (const float*)d_in[14];
  const float* w2   = (const float*)d_in[15];
  const float* b2   = (const float*)d_in[16];
  float* out = (float*)d_out;

  // workspace layout (ushort units), span ~151.3 MiB
  ushort* ws = (ushort*)d_ws;
  const size_t nD = (size_t)kNT * kD;                  // 9437184
  const size_t nQK = (size_t)kB * kNH * 1024 * kEP;    // 12582912
  const size_t nVT = (size_t)kB * kNH * kEV * 1024;    // 10485760
  ushort* hb  = ws;                 // LN1 out; reused as attn-out (ob)
  ushort* qp  = hb + nD;            // reused as LN2 out (h2b)
  ushort* kp  = qp + nQK;           // reused (with vt) as MLP fb chunk
  ushort* vt  = kp + nQK;
  ushort* wqb = vt + nVT;
  ushort* wkb = wqb + (size_t)kD * kD;
  ushort* wvb = wkb + (size_t)kD * kD;
  ushort* wob = wvb + (size_t)kD * kD;
  ushort* w1b = wob + (size_t)kD * kD;     // [4352][1152] (rows >=4304 unused)
  ushort* w2b = w1b + (size_t)kFP * kD;    // [1152][4352] (pad cols zeroed)
  float*  x1  = (float*)(w2b + (size_t)kD * kFP);
  float*  b1b = x1 + nD;
  ushort* ob  = hb;
  ushort* h2b = qp;
  ushort* fb  = kp;                 // [8192][2176] bf16 chunk (fits kp+vt)

  const dim3 blk(256);
  const dim3 gqkv(64, 9);           // N=8192/128 x M=1152/128
  const dim3 gm1(64, 17);           // M=2176/128
  const dim3 ga(4, 16, 8);

  // weight/bias conversion (per-launch; inputs restored each call)
  const int nDD4 = kD * kD / 4;
  cvt4_kernel<<<(nDD4 + 255) / 256, blk, 0, stream>>>(wq, wqb, nDD4);
  cvt4_kernel<<<(nDD4 + 255) / 256, blk, 0, stream>>>(wk, wkb, nDD4);
  cvt4_kernel<<<(nDD4 + 255) / 256, blk, 0, stream>>>(wv, wvb, nDD4);
  cvt4_kernel<<<(nDD4 + 255) / 256, blk, 0, stream>>>(wo, wob, nDD4);
  const int nW14 = kF * kD / 4;
  cvt4_kernel<<<(nW14 + 255) / 256, blk, 0, stream>>>(w1, w1b, nW14);
  cvtw2_kernel<<<(kD * (kFP / 4) + 255) / 256, blk, 0, stream>>>(w2, w2b);
  b1pad_kernel<<<(kFP + 255) / 256, blk, 0, stream>>>(b1, b1b);
  zfill_kernel<<<16384, blk, 0, stream>>>(kp, vt);

  ln_kernel<<<kNT, blk, 0, stream>>>(x, ln1w, ln1b, hb);
  gemm_mfma<2, 0, 1, 0, 1><<<gqkv, blk, 0, stream>>>(hb, wqb, bq, nullptr, qp, kD, kD, kD);
  gemm_mfma<2, 0, 1, 0, 0><<<gqkv, blk, 0, stream>>>(hb, wkb, bk, nullptr, kp, kD, kD, kD);
  gemm_mfma<3, 0, 1, 0, 0><<<gqkv, blk, 0, stream>>>(hb, wvb, bv, nullptr, vt, kD, kD, kD);
  attn_kernel<<<ga, blk, 0, stream>>>(qp, kp, vt, ob);
  gemm_mfma<0, 0, 1, 1, 0><<<gqkv, blk, 0, stream>>>(ob, wob, bo, x, x1, kD, kD, kD);
  ln_kernel<<<kNT, blk, 0, stream>>>(x1, ln2w, ln2b, h2b);
  // MLP in two F-chunks of 2176 (fb overlays kp+vt)
  gemm_mfma<1, 1, 1, 0, 0><<<gm1, blk, 0, stream>>>(h2b, w1b, b1b, nullptr, fb, kFC, kD, kD);
  gemm_mfma<0, 0, 1, 1, 0><<<gqkv, blk, 0, stream>>>(fb, w2b, b2, x1, out, kD, kFC, kFP);
  gemm_mfma<1, 1, 1, 0, 0><<<gm1, blk, 0, stream>>>(h2b, w1b + (size_t)kFC * kD, b1b + kFC, nullptr, fb, kFC, kD, kD);
  gemm_mfma<0, 0, 0, 1, 0><<<gqkv, blk, 0, stream>>>(fb, w2b + kFC, nullptr, out, out, kD, kFC, kFP);
}

// Round 6
// 873.577 us; speedup vs baseline: 5.4119x; 1.1244x over previous
//
#include <hip/hip_runtime.h>
#include <cstddef>
#include <cstdint>

// SigLIP block, bf16-MFMA round 5 (resubmit — R5 never ran; broker timeout):
//  - attention: swapped QK^T (S^T orientation), P kept in registers (no LDS P),
//    softmax reduce = in-lane 16 + 2 shfl; P->PV A-frags via 16 shfl + selects.
//  - QKV projection merged into one GEMM (M=3456) for grid-tail efficiency.
// B=8 T=1024 D=1152 NH=16 F=4304 HD=72.

constexpr int kB = 8, kT = 1024, kD = 1152, kNH = 16, kF = 4304, kHD = 72;
constexpr int kNT = kB * kT;     // 8192
constexpr int kFP = 4352;        // padded F (34*128)
constexpr int kEP = 96;          // padded head-dim for Q/K (3*32)
constexpr int kEV = 80;          // padded head-dim rows for V^T (5*16)
constexpr int kFC = 2176;        // MLP chunk (kFP/2 = 17*128)

typedef short bf16x8 __attribute__((ext_vector_type(8)));
typedef float f32x4 __attribute__((ext_vector_type(4)));

__device__ __forceinline__ ushort f2bf(float f) {
  union { float f; uint u; } a; a.f = f;
  const uint r = a.u + 0x7FFFu + ((a.u >> 16) & 1u);   // RNE (finite inputs)
  return (ushort)(r >> 16);
}
__device__ __forceinline__ float gelu_tanh(float x) {
  const float u = 0.7978845608028654f * (x + 0.044715f * x * x * x);
  return 0.5f * x * (1.0f + tanhf(u));
}
#define GLL16(g, s) __builtin_amdgcn_global_load_lds( \
    (const __attribute__((address_space(1))) void*)(g), \
    (__attribute__((address_space(3))) void*)(s), 16, 0, 0)

// ---------------------------------------------------------------- LayerNorm
__global__ __launch_bounds__(256) void ln_kernel(const float* __restrict__ in,
                                                 const float* __restrict__ w,
                                                 const float* __restrict__ b,
                                                 ushort* __restrict__ out) {
  const int row = blockIdx.x;
  const float4* r4 = reinterpret_cast<const float4*>(in + (size_t)row * kD);
  const float4* w4 = reinterpret_cast<const float4*>(w);
  const float4* b4 = reinterpret_cast<const float4*>(b);
  const int t = threadIdx.x;                 // 288 float4/row: t and t+256 (t<32)
  float4 v0 = r4[t];
  float4 v1 = make_float4(0.f, 0.f, 0.f, 0.f);
  const bool second = (t < kD / 4 - 256);
  if (second) v1 = r4[t + 256];
  float s  = v0.x + v0.y + v0.z + v0.w + v1.x + v1.y + v1.z + v1.w;
  float ss = v0.x * v0.x + v0.y * v0.y + v0.z * v0.z + v0.w * v0.w +
             v1.x * v1.x + v1.y * v1.y + v1.z * v1.z + v1.w * v1.w;
  #pragma unroll
  for (int m = 1; m <= 32; m <<= 1) { s += __shfl_xor(s, m); ss += __shfl_xor(ss, m); }
  __shared__ float red[8];
  const int wave = t >> 6;
  if ((t & 63) == 0) { red[wave] = s; red[4 + wave] = ss; }
  __syncthreads();
  s  = red[0] + red[1] + red[2] + red[3];
  ss = red[4] + red[5] + red[6] + red[7];
  const float mean = s * (1.0f / kD);
  const float var  = ss * (1.0f / kD) - mean * mean;
  const float rs   = rsqrtf(var + 1e-5f);
  ushort4* o4 = reinterpret_cast<ushort4*>(out + (size_t)row * kD);
  {
    float4 W = w4[t], Bv = b4[t];
    ushort4 r;
    r.x = f2bf((v0.x - mean) * rs * W.x + Bv.x);
    r.y = f2bf((v0.y - mean) * rs * W.y + Bv.y);
    r.z = f2bf((v0.z - mean) * rs * W.z + Bv.z);
    r.w = f2bf((v0.w - mean) * rs * W.w + Bv.w);
    o4[t] = r;
  }
  if (second) {
    float4 W = w4[t + 256], Bv = b4[t + 256];
    ushort4 r;
    r.x = f2bf((v1.x - mean) * rs * W.x + Bv.x);
    r.y = f2bf((v1.y - mean) * rs * W.y + Bv.y);
    r.z = f2bf((v1.z - mean) * rs * W.z + Bv.z);
    r.w = f2bf((v1.w - mean) * rs * W.w + Bv.w);
    o4[t + 256] = r;
  }
}

// ---------------------------------------------------------------- converters
__global__ __launch_bounds__(256) void cvt4_kernel(const float* __restrict__ src,
                                                   ushort* __restrict__ dst, int n4) {
  const int i = blockIdx.x * 256 + threadIdx.x;
  if (i < n4) {
    const float4 v = reinterpret_cast<const float4*>(src)[i];
    ushort4 r = { f2bf(v.x), f2bf(v.y), f2bf(v.z), f2bf(v.w) };
    reinterpret_cast<ushort4*>(dst)[i] = r;
  }
}
// w2 [1152][4304] -> w2b [1152][4352], pad cols MUST be zero.
__global__ __launch_bounds__(256) void cvtw2_kernel(const float* __restrict__ src,
                                                    ushort* __restrict__ dst) {
  const int i = blockIdx.x * 256 + threadIdx.x;
  if (i >= kD * (kFP / 4)) return;
  const int r = i / (kFP / 4), c4 = i % (kFP / 4);
  const int c = c4 * 4;
  ushort4 o;
  if (c < kF) {
    const float4 v = *reinterpret_cast<const float4*>(src + (size_t)r * kF + c);
    o = { f2bf(v.x), f2bf(v.y), f2bf(v.z), f2bf(v.w) };
  } else o = { 0, 0, 0, 0 };
  reinterpret_cast<ushort4*>(dst + (size_t)r * kFP)[c4] = o;
}
// b1 pad (4352 floats) + zero w1b pad rows [4304,4352) x 1152
__global__ __launch_bounds__(256) void b1pad_kernel(const float* __restrict__ src,
                                                    float* __restrict__ dst,
                                                    ushort* __restrict__ w1b) {
  const int i = blockIdx.x * 256 + threadIdx.x;
  if (i < kFP) dst[i] = (i < kF) ? src[i] : 0.f;
  const int j = i - kFP;
  if (j >= 0 && j < (kFP - kF) * kD) w1b[(size_t)kF * kD + j] = 0;
}
// zero the K e-pad cols [72,96) and V^T e-pad rows [72,80)
__global__ __launch_bounds__(256) void zfill_kernel(ushort* __restrict__ kp,
                                                    ushort* __restrict__ vt) {
  const int i = blockIdx.x * 256 + threadIdx.x;
  const int nk = 131072 * 24;
  if (i < nk) {
    const int row = i / 24, c = 72 + i % 24;
    kp[(size_t)row * kEP + c] = 0;
  } else {
    const int j = i - nk;
    if (j < 131072 * 8) {
      const int bh = j >> 13, rem = j & 8191;
      const int e = 72 + (rem >> 10), s = rem & 1023;
      vt[((size_t)bh * kEV + e) * 1024 + s] = 0;
    }
  }
}

// ------------------------------------------------------------- MFMA GEMM
// C = [res +] [gelu] (A @ W^T + bias).  A [N][K] bf16, W rows stride ldw bf16.
// 128x128 tile, BK=32, 4 waves (2x2), 4x4 16x16x32 frags/wave. Dims exact.
// MODE: 0 = f32 [N][M]; 1 = bf16 [N][M];
//       4 = merged QKV: M=3456, proj=bm/9 (0:Q scaled->qp, 1:K->kp, 2:V^T->vt)
template <int MODE, int GELU_, int BIAS_, int RES_>
__global__ __launch_bounds__(256) void gemm_mfma(
    const ushort* __restrict__ A, const ushort* __restrict__ W,
    const float* __restrict__ bias, const float* __restrict__ bias2,
    const float* __restrict__ bias3, const float* __restrict__ res,
    void* __restrict__ Cout, void* __restrict__ C2, void* __restrict__ C3,
    int M, int K, int ldw) {
  __shared__ __align__(16) ushort As[128 * 32];
  __shared__ __align__(16) ushort Bs[128 * 32];
  const int tid = threadIdx.x;
  const int l = tid & 63, w = tid >> 6;
  const int lr = l & 15, lg = l >> 4;
  const int wm = w >> 1, wn = w & 1;
  const int bn = blockIdx.x, bm = blockIdx.y;
  f32x4 acc[4][4] = {};
  const int srow = 32 * w + (l >> 2);       // staging row (+0 / +16 per issue)
  const int scol = (l & 3) << 3;            // staging k-offset (elements)
  const ushort* Ag = A + (size_t)(bn * 128 + srow) * K + scol;
  const ushort* Wg = W + (size_t)(bm * 128 + srow) * ldw + scol;
  for (int k0 = 0; k0 < K; k0 += 32) {
    __syncthreads();
    #pragma unroll
    for (int i = 0; i < 2; i++) {
      GLL16(Ag + (size_t)(16 * i) * K + k0, &As[(32 * w + 16 * i) * 32]);
      GLL16(Wg + (size_t)(16 * i) * ldw + k0, &Bs[(32 * w + 16 * i) * 32]);
    }
    __syncthreads();
    bf16x8 af[4], bf[4];
    #pragma unroll
    for (int mf = 0; mf < 4; mf++)
      af[mf] = *(const bf16x8*)&As[(wm * 64 + mf * 16 + lr) * 32 + lg * 8];
    #pragma unroll
    for (int nf = 0; nf < 4; nf++)
      bf[nf] = *(const bf16x8*)&Bs[(wn * 64 + nf * 16 + lr) * 32 + lg * 8];
    #pragma unroll
    for (int mf = 0; mf < 4; mf++)
      #pragma unroll
      for (int nf = 0; nf < 4; nf++)
        acc[mf][nf] = __builtin_amdgcn_mfma_f32_16x16x32_bf16(af[mf], bf[nf], acc[mf][nf], 0, 0, 0);
  }
  // epilogue: C layout col = lane&15, row = (lane>>4)*4 + j
  if (MODE == 4) {
    const int proj = bm / 9;                       // uniform per block (1152=9*128)
    const float* bp = proj == 0 ? bias : (proj == 1 ? bias2 : bias3);
    ushort* dstp = (ushort*)(proj == 0 ? Cout : (proj == 1 ? C2 : C3));
    #pragma unroll
    for (int mf = 0; mf < 4; mf++) {
      #pragma unroll
      for (int nf = 0; nf < 4; nf++) {
        const int c = bm * 128 + wn * 64 + nf * 16 + lr;
        const int cl = c - proj * kD;
        const int jj = cl / 72, e = cl - jj * 72;
        const float bv = bp[cl];
        #pragma unroll
        for (int j = 0; j < 4; j++) {
          const int r = bn * 128 + wm * 64 + mf * 16 + lg * 4 + j;
          float v = acc[mf][nf][j] + bv;
          if (proj == 0) v *= 0.11785113019775793f;   // 72^-0.5 folded into q
          const int b = r >> 10, t = r & 1023;
          const int h = t >> 6, u = t & 63;
          const int s = u * 16 + jj, bh = b * 16 + h;
          const size_t dst = (proj < 2) ? ((size_t)bh * 1024 + s) * kEP + e
                                        : ((size_t)bh * kEV + e) * 1024 + s;
          dstp[dst] = f2bf(v);
        }
      }
    }
    return;
  }
  #pragma unroll
  for (int mf = 0; mf < 4; mf++) {
    #pragma unroll
    for (int nf = 0; nf < 4; nf++) {
      const int c = bm * 128 + wn * 64 + nf * 16 + lr;
      const float bv = BIAS_ ? bias[c] : 0.f;
      #pragma unroll
      for (int j = 0; j < 4; j++) {
        const int r = bn * 128 + wm * 64 + mf * 16 + lg * 4 + j;
        float v = acc[mf][nf][j] + bv;
        if (GELU_) v = gelu_tanh(v);
        if (RES_) v += res[(size_t)r * M + c];
        if (MODE == 0) ((float*)Cout)[(size_t)r * M + c] = v;
        else           ((ushort*)Cout)[(size_t)r * M + c] = f2bf(v);
      }
    }
  }
}

// ------------------------------------------------------- MFMA flash attention
// Swapped orientation: S^T = mfma(K, Q) so query = output col (lane&15),
// key = output row. Softmax per query: 16 in-lane values + shfl_xor(16,32).
// P stays in registers: packed to bf16 pairs and moved into PV A-fragment
// layout with shuffles (no LDS P buffer, no extra barrier).
// qp/kp: [bh][1024][96] bf16 (q prescaled; kp e-pad zeroed). vt: [bh][80][1024]
// (rows 72..79 zeroed, XOR-swizzle staged). ob written TRANSPOSED:
// O[bh][s][e] -> ob[(b*1024+s)*1152 + h*72 + e].
__global__ __launch_bounds__(256, 2) void attn_kernel(
    const ushort* __restrict__ qp, const ushort* __restrict__ kp,
    const ushort* __restrict__ vt, ushort* __restrict__ ob) {
  __shared__ __align__(16) ushort Kt[64 * 96];      // 12288 B
  __shared__ __align__(16) ushort Vt[80 * 64];      // 10240 B (swizzled)
  const int tid = threadIdx.x, l = tid & 63, w = tid >> 6;
  const int lr = l & 15, lg = l >> 4;
  const int qb = blockIdx.x, hh = blockIdx.y, bb = blockIdx.z;
  const int bh = bb * 16 + hh;
  const int s0 = qb * 256 + w * 64;
  // Q fragments (B-operand): qf[qi][ks] = Q[row s0+qi*16+lr][ks*32+lg*8 ..+8]
  bf16x8 qf[4][3];
  const ushort* qbase = qp + (size_t)bh * 1024 * kEP;
  #pragma unroll
  for (int qi = 0; qi < 4; qi++)
    #pragma unroll
    for (int ks = 0; ks < 3; ks++)
      qf[qi][ks] = *(const bf16x8*)(qbase + (size_t)(s0 + qi * 16 + lr) * kEP + ks * 32 + lg * 8);
  float mstate[4], lstate[4];                 // for query q = qi*16 + lr
  #pragma unroll
  for (int i = 0; i < 4; i++) { mstate[i] = -1e30f; lstate[i] = 0.f; }
  f32x4 oacc[4][5] = {};                      // [qi][ei]; elem j: q = qi*16+lg*4+j
  const ushort* ktile0 = kp + (size_t)bh * 1024 * kEP;
  const ushort* vbase  = vt + (size_t)bh * kEV * 1024;
  const int srcA = lr + 32 * (lg & 1);        // P-assembly shuffle sources
  const int srcB = srcA + 16;
  const int hi = lg >> 1;
  const int rmap = (lg << 4) + (lg << 2);     // lane holding alpha for q=lg*4+j

  for (int kt = 0; kt < 16; kt++) {
    __syncthreads();                       // prior tile's Kt/Vt reads done
    {  // K tile: contiguous 64x96 bf16 = 12KB, 12 linear issues (3/wave)
      const ushort* kg = ktile0 + (size_t)kt * 64 * kEP;
      #pragma unroll
      for (int i = 0; i < 3; i++) {
        const int is = w * 3 + i;
        GLL16(kg + is * 512 + l * 8, &Kt[is * 512]);
      }
    }
    {  // V^T tile: 80 rows x 128B, row-stride 2048B, XOR-swizzled source
      #pragma unroll
      for (int i = 0; i < 3; i++) {
        const int is = w + i * 4;
        if (is < 10) {
          const int e = is * 8 + (l >> 3);
          const int cg = (l & 7) ^ (e & 7);
          GLL16(vbase + (size_t)e * 1024 + kt * 64 + cg * 8, &Vt[is * 512]);
        }
      }
    }
    __syncthreads();
    // ---- S^T = K Q^T : sacc[si][qi], col=query(lr), row=key(si*16+lg*4+j)
    f32x4 sacc[4][4];
    #pragma unroll
    for (int si = 0; si < 4; si++)
      #pragma unroll
      for (int qi = 0; qi < 4; qi++)
        sacc[si][qi] = (f32x4){0.f, 0.f, 0.f, 0.f};
    #pragma unroll
    for (int ks = 0; ks < 3; ks++) {
      bf16x8 kf[4];
      #pragma unroll
      for (int si = 0; si < 4; si++)
        kf[si] = *(const bf16x8*)&Kt[(si * 16 + lr) * 96 + ks * 32 + lg * 8];
      #pragma unroll
      for (int si = 0; si < 4; si++)
        #pragma unroll
        for (int qi = 0; qi < 4; qi++)
          sacc[si][qi] = __builtin_amdgcn_mfma_f32_16x16x32_bf16(kf[si], qf[qi][ks], sacc[si][qi], 0, 0, 0);
    }
    // ---- per q-tile: softmax + P assembly + PV
    #pragma unroll
    for (int qi = 0; qi < 4; qi++) {
      // max over this lane's 16 keys, then across the 4 lg lanes
      float mx = sacc[0][qi][0];
      #pragma unroll
      for (int si = 0; si < 4; si++)
        #pragma unroll
        for (int j = 0; j < 4; j++) mx = fmaxf(mx, sacc[si][qi][j]);
      mx = fmaxf(mx, __shfl_xor(mx, 16));
      mx = fmaxf(mx, __shfl_xor(mx, 32));
      const float mo = mstate[qi], mn = fmaxf(mo, mx);
      float sum = 0.f;
      #pragma unroll
      for (int si = 0; si < 4; si++)
        #pragma unroll
        for (int j = 0; j < 4; j++) {
          const float p = __expf(sacc[si][qi][j] - mn);
          sacc[si][qi][j] = p;
          sum += p;
        }
      sum += __shfl_xor(sum, 16);
      sum += __shfl_xor(sum, 32);
      const float al = __expf(mo - mn);       // uniform across the 4 lg lanes
      lstate[qi] = lstate[qi] * al + sum;
      mstate[qi] = mn;
      // rescale O for this q-tile (element j belongs to q = qi*16+lg*4+j)
      #pragma unroll
      for (int j = 0; j < 4; j++) {
        const float alj = __shfl(al, rmap + j);
        #pragma unroll
        for (int ei = 0; ei < 5; ei++) oacc[qi][ei][j] *= alj;
      }
      // pack P to bf16 pairs: wlo=(j0,j1) whi=(j2,j3) per key-tile si
      uint wlo[4], whi[4];
      #pragma unroll
      for (int si = 0; si < 4; si++) {
        wlo[si] = (uint)f2bf(sacc[si][qi][0]) | ((uint)f2bf(sacc[si][qi][1]) << 16);
        whi[si] = (uint)f2bf(sacc[si][qi][2]) | ((uint)f2bf(sacc[si][qi][3]) << 16);
      }
      // shuffle into PV A-fragment layout:
      // lane (lr,lg) needs P[q=qi*16+lr][s = ks2*32 + lg*8 ..+8]
      uint A0[4], A1[4], A2[4], A3[4];
      #pragma unroll
      for (int si = 0; si < 4; si++) {
        A0[si] = (uint)__shfl((int)wlo[si], srcA);
        A1[si] = (uint)__shfl((int)whi[si], srcA);
        A2[si] = (uint)__shfl((int)wlo[si], srcB);
        A3[si] = (uint)__shfl((int)whi[si], srcB);
      }
      union U { uint u[4]; bf16x8 v; } p0, p1;
      p0.u[0] = hi ? A0[1] : A0[0];  p0.u[1] = hi ? A1[1] : A1[0];
      p0.u[2] = hi ? A2[1] : A2[0];  p0.u[3] = hi ? A3[1] : A3[0];
      p1.u[0] = hi ? A0[3] : A0[2];  p1.u[1] = hi ? A1[3] : A1[2];
      p1.u[2] = hi ? A2[3] : A2[2];  p1.u[3] = hi ? A3[3] : A3[2];
      // ---- O[q][e] += P V : A = P frags, B = V^T frags (swizzled LDS reads)
      #pragma unroll
      for (int ei = 0; ei < 5; ei++) {
        const int e = ei * 16 + lr;
        const int sw = e & 7;
        bf16x8 vb0 = *(const bf16x8*)&Vt[e * 64 + ((0 + lg) ^ sw) * 8];
        bf16x8 vb1 = *(const bf16x8*)&Vt[e * 64 + ((4 + lg) ^ sw) * 8];
        oacc[qi][ei] = __builtin_amdgcn_mfma_f32_16x16x32_bf16(p0.v, vb0, oacc[qi][ei], 0, 0, 0);
        oacc[qi][ei] = __builtin_amdgcn_mfma_f32_16x16x32_bf16(p1.v, vb1, oacc[qi][ei], 0, 0, 0);
      }
    }
  }
  // ---- epilogue: O /= l; scatter TRANSPOSED: ob[(b*1024+s)*1152 + h*72 + e]
  #pragma unroll
  for (int qi = 0; qi < 4; qi++) {
    const float rli = 1.f / lstate[qi];
    float lij[4];
    #pragma unroll
    for (int j = 0; j < 4; j++) lij[j] = __shfl(rli, rmap + j);
    #pragma unroll
    for (int ei = 0; ei < 5; ei++) {
      const int e = ei * 16 + lr;
      if (e < 72) {
        #pragma unroll
        for (int j = 0; j < 4; j++) {
          const int s = s0 + qi * 16 + lg * 4 + j;
          ob[((size_t)bb * 1024 + s) * kD + hh * kHD + e] =
              f2bf(oacc[qi][ei][j] * lij[j]);
        }
      }
    }
  }
}

// ----------------------------------------------------------------- launch
extern "C" void kernel_launch(void* const* d_in, const int* in_sizes, int n_in,
                              void* d_out, int out_size, void* d_ws, size_t ws_size,
                              hipStream_t stream) {
  const float* x    = (const float*)d_in[0];
  const float* ln1w = (const float*)d_in[1];
  const float* ln1b = (const float*)d_in[2];
  const float* wq   = (const float*)d_in[3];
  const float* bq   = (const float*)d_in[4];
  const float* wk   = (const float*)d_in[5];
  const float* bk   = (const float*)d_in[6];
  const float* wv   = (const float*)d_in[7];
  const float* bv   = (const float*)d_in[8];
  const float* wo   = (const float*)d_in[9];
  const float* bo   = (const float*)d_in[10];
  const float* ln2w = (const float*)d_in[11];
  const float* ln2b = (const float*)d_in[12];
  const float* w1   = (const float*)d_in[13];
  const float* b1   = (const float*)d_in[14];
  const float* w2   = (const float*)d_in[15];
  const float* b2   = (const float*)d_in[16];
  float* out = (float*)d_out;

  // workspace layout (ushort units), span ~151.3 MiB (same as round 4)
  ushort* ws = (ushort*)d_ws;
  const size_t nD = (size_t)kNT * kD;                  // 9437184
  const size_t nQK = (size_t)kB * kNH * 1024 * kEP;    // 12582912
  const size_t nVT = (size_t)kB * kNH * kEV * 1024;    // 10485760
  ushort* hb  = ws;                 // LN1 out; reused as attn-out (ob)
  ushort* qp  = hb + nD;            // reused as LN2 out (h2b)
  ushort* kp  = qp + nQK;           // reused (with vt) as MLP fb chunk
  ushort* vt  = kp + nQK;
  ushort* wqb = vt + nVT;           // wqb/wkb/wvb contiguous = merged W [3456][1152]
  ushort* wkb = wqb + (size_t)kD * kD;
  ushort* wvb = wkb + (size_t)kD * kD;
  ushort* wob = wvb + (size_t)kD * kD;
  ushort* w1b = wob + (size_t)kD * kD;     // [4352][1152] (pad rows zeroed)
  ushort* w2b = w1b + (size_t)kFP * kD;    // [1152][4352] (pad cols zeroed)
  float*  x1  = (float*)(w2b + (size_t)kD * kFP);
  float*  b1b = x1 + nD;
  ushort* ob  = hb;
  ushort* h2b = qp;
  ushort* fb  = kp;                 // [8192][2176] bf16 chunk (fits kp+vt)

  const dim3 blk(256);
  const dim3 gqkv(64, 27);          // merged QKV: N=8192/128 x M=3456/128
  const dim3 go(64, 9);             // D-output GEMMs
  const dim3 gm1(64, 17);           // M=2176/128
  const dim3 ga(4, 16, 8);

  // weight/bias conversion (per-launch; inputs restored each call)
  const int nDD4 = kD * kD / 4;
  cvt4_kernel<<<(nDD4 + 255) / 256, blk, 0, stream>>>(wq, wqb, nDD4);
  cvt4_kernel<<<(nDD4 + 255) / 256, blk, 0, stream>>>(wk, wkb, nDD4);
  cvt4_kernel<<<(nDD4 + 255) / 256, blk, 0, stream>>>(wv, wvb, nDD4);
  cvt4_kernel<<<(nDD4 + 255) / 256, blk, 0, stream>>>(wo, wob, nDD4);
  const int nW14 = kF * kD / 4;
  cvt4_kernel<<<(nW14 + 255) / 256, blk, 0, stream>>>(w1, w1b, nW14);
  cvtw2_kernel<<<(kD * (kFP / 4) + 255) / 256, blk, 0, stream>>>(w2, w2b);
  b1pad_kernel<<<(kFP + (kFP - kF) * kD + 255) / 256, blk, 0, stream>>>(b1, b1b, w1b);
  zfill_kernel<<<16384, blk, 0, stream>>>(kp, vt);

  ln_kernel<<<kNT, blk, 0, stream>>>(x, ln1w, ln1b, hb);
  gemm_mfma<4, 0, 1, 0><<<gqkv, blk, 0, stream>>>(hb, wqb, bq, bk, bv, nullptr,
                                                  qp, kp, vt, kD, kD, kD);
  attn_kernel<<<ga, blk, 0, stream>>>(qp, kp, vt, ob);
  gemm_mfma<0, 0, 1, 1><<<go, blk, 0, stream>>>(ob, wob, bo, nullptr, nullptr, x,
                                                x1, nullptr, nullptr, kD, kD, kD);
  ln_kernel<<<kNT, blk, 0, stream>>>(x1, ln2w, ln2b, h2b);
  // MLP in two F-chunks of 2176 (fb overlays kp+vt)
  gemm_mfma<1, 1, 1, 0><<<gm1, blk, 0, stream>>>(h2b, w1b, b1b, nullptr, nullptr, nullptr,
                                                 fb, nullptr, nullptr, kFC, kD, kD);
  gemm_mfma<0, 0, 1, 1><<<go, blk, 0, stream>>>(fb, w2b, b2, nullptr, nullptr, x1,
                                                out, nullptr, nullptr, kD, kFC, kFP);
  gemm_mfma<1, 1, 1, 0><<<gm1, blk, 0, stream>>>(h2b, w1b + (size_t)kFC * kD, b1b + kFC,
                                                 nullptr, nullptr, nullptr,
                                                 fb, nullptr, nullptr, kFC, kD, kD);
  gemm_mfma<0, 0, 0, 1><<<go, blk, 0, stream>>>(fb, w2b + kFC, nullptr, nullptr, nullptr,
                                                out, out, nullptr, nullptr, kD, kFC, kFP);
}

// Round 7
// 790.485 us; speedup vs baseline: 5.9808x; 1.1051x over previous
//
#include <hip/hip_runtime.h>
#include <cstddef>
#include <cstdint>

// SigLIP block, round 7: all GEMMs moved to a 256x256 counted-vmcnt pipelined
// MFMA kernel (gemm256); attention/LN/converters unchanged from round 6.
// B=8 T=1024 D=1152 NH=16 F=4304 HD=72.

constexpr int kB = 8, kT = 1024, kD = 1152, kNH = 16, kF = 4304, kHD = 72;
constexpr int kNT = kB * kT;     // 8192
constexpr int kFP = 4352;        // padded F (17*256)
constexpr int kEP = 96;          // padded head-dim for Q/K (3*32)
constexpr int kEV = 80;          // padded head-dim rows for V^T (5*16)

typedef short bf16x8 __attribute__((ext_vector_type(8)));
typedef float f32x4 __attribute__((ext_vector_type(4)));

__device__ __forceinline__ ushort f2bf(float f) {
  union { float f; uint u; } a; a.f = f;
  const uint r = a.u + 0x7FFFu + ((a.u >> 16) & 1u);   // RNE (finite inputs)
  return (ushort)(r >> 16);
}
__device__ __forceinline__ float gelu_tanh(float x) {
  const float u = 0.7978845608028654f * (x + 0.044715f * x * x * x);
  return 0.5f * x * (1.0f + tanhf(u));
}
#define GLL16(g, s) __builtin_amdgcn_global_load_lds( \
    (const __attribute__((address_space(1))) void*)(g), \
    (__attribute__((address_space(3))) void*)(s), 16, 0, 0)

// ---------------------------------------------------------------- LayerNorm
__global__ __launch_bounds__(256) void ln_kernel(const float* __restrict__ in,
                                                 const float* __restrict__ w,
                                                 const float* __restrict__ b,
                                                 ushort* __restrict__ out) {
  const int row = blockIdx.x;
  const float4* r4 = reinterpret_cast<const float4*>(in + (size_t)row * kD);
  const float4* w4 = reinterpret_cast<const float4*>(w);
  const float4* b4 = reinterpret_cast<const float4*>(b);
  const int t = threadIdx.x;
  float4 v0 = r4[t];
  float4 v1 = make_float4(0.f, 0.f, 0.f, 0.f);
  const bool second = (t < kD / 4 - 256);
  if (second) v1 = r4[t + 256];
  float s  = v0.x + v0.y + v0.z + v0.w + v1.x + v1.y + v1.z + v1.w;
  float ss = v0.x * v0.x + v0.y * v0.y + v0.z * v0.z + v0.w * v0.w +
             v1.x * v1.x + v1.y * v1.y + v1.z * v1.z + v1.w * v1.w;
  #pragma unroll
  for (int m = 1; m <= 32; m <<= 1) { s += __shfl_xor(s, m); ss += __shfl_xor(ss, m); }
  __shared__ float red[8];
  const int wave = t >> 6;
  if ((t & 63) == 0) { red[wave] = s; red[4 + wave] = ss; }
  __syncthreads();
  s  = red[0] + red[1] + red[2] + red[3];
  ss = red[4] + red[5] + red[6] + red[7];
  const float mean = s * (1.0f / kD);
  const float var  = ss * (1.0f / kD) - mean * mean;
  const float rs   = rsqrtf(var + 1e-5f);
  ushort4* o4 = reinterpret_cast<ushort4*>(out + (size_t)row * kD);
  {
    float4 W = w4[t], Bv = b4[t];
    ushort4 r;
    r.x = f2bf((v0.x - mean) * rs * W.x + Bv.x);
    r.y = f2bf((v0.y - mean) * rs * W.y + Bv.y);
    r.z = f2bf((v0.z - mean) * rs * W.z + Bv.z);
    r.w = f2bf((v0.w - mean) * rs * W.w + Bv.w);
    o4[t] = r;
  }
  if (second) {
    float4 W = w4[t + 256], Bv = b4[t + 256];
    ushort4 r;
    r.x = f2bf((v1.x - mean) * rs * W.x + Bv.x);
    r.y = f2bf((v1.y - mean) * rs * W.y + Bv.y);
    r.z = f2bf((v1.z - mean) * rs * W.z + Bv.z);
    r.w = f2bf((v1.w - mean) * rs * W.w + Bv.w);
    o4[t + 256] = r;
  }
}

// ---------------------------------------------------------------- converters
__global__ __launch_bounds__(256) void cvt4_kernel(const float* __restrict__ src,
                                                   ushort* __restrict__ dst, int n4) {
  const int i = blockIdx.x * 256 + threadIdx.x;
  if (i < n4) {
    const float4 v = reinterpret_cast<const float4*>(src)[i];
    ushort4 r = { f2bf(v.x), f2bf(v.y), f2bf(v.z), f2bf(v.w) };
    reinterpret_cast<ushort4*>(dst)[i] = r;
  }
}
// w2 [1152][4304] -> w2b [1152][4352], pad cols MUST be zero.
__global__ __launch_bounds__(256) void cvtw2_kernel(const float* __restrict__ src,
                                                    ushort* __restrict__ dst) {
  const int i = blockIdx.x * 256 + threadIdx.x;
  if (i >= kD * (kFP / 4)) return;
  const int r = i / (kFP / 4), c4 = i % (kFP / 4);
  const int c = c4 * 4;
  ushort4 o;
  if (c < kF) {
    const float4 v = *reinterpret_cast<const float4*>(src + (size_t)r * kF + c);
    o = { f2bf(v.x), f2bf(v.y), f2bf(v.z), f2bf(v.w) };
  } else o = { 0, 0, 0, 0 };
  reinterpret_cast<ushort4*>(dst + (size_t)r * kFP)[c4] = o;
}
// b1 pad (4352 floats) + zero w1b pad rows [4304,4352) x 1152
__global__ __launch_bounds__(256) void b1pad_kernel(const float* __restrict__ src,
                                                    float* __restrict__ dst,
                                                    ushort* __restrict__ w1b) {
  const int i = blockIdx.x * 256 + threadIdx.x;
  if (i < kFP) dst[i] = (i < kF) ? src[i] : 0.f;
  const int j = i - kFP;
  if (j >= 0 && j < (kFP - kF) * kD) w1b[(size_t)kF * kD + j] = 0;
}
// zero the K e-pad cols [72,96) and V^T e-pad rows [72,80)
__global__ __launch_bounds__(256) void zfill_kernel(ushort* __restrict__ kp,
                                                    ushort* __restrict__ vt) {
  const int i = blockIdx.x * 256 + threadIdx.x;
  const int nk = 131072 * 24;
  if (i < nk) {
    const int row = i / 24, c = 72 + i % 24;
    kp[(size_t)row * kEP + c] = 0;
  } else {
    const int j = i - nk;
    if (j < 131072 * 8) {
      const int bh = j >> 13, rem = j & 8191;
      const int e = 72 + (rem >> 10), s = rem & 1023;
      vt[((size_t)bh * kEV + e) * 1024 + s] = 0;
    }
  }
}

// ------------------------------------------------------- 256x256 MFMA GEMM
// C = [res +] [gelu] (A @ W^T + bias).  A [N][K] bf16, W rows stride ldw bf16.
// 8 waves (2x4), per-wave 128x64 (8x4 16x16x32 frags). BK=32 K-slices,
// double-buffered 64KB LDS, counted vmcnt (never same-iteration drain),
// A-fragment register double-buffer overlapping ds_read with MFMA.
// LDS XOR swizzle: 16B-chunk ^= row&3 within each 64B row (write-src + read).
// MODE: 0 = f32 out + res + bias (guard c<Mreal); 1 = bf16 out (+gelu);
//       4 = merged QKV scatter (guard c<3456).
template <int MODE, int GELU_>
__global__ __launch_bounds__(512, 2) void gemm256(
    const ushort* __restrict__ A, const ushort* __restrict__ W,
    const float* __restrict__ bias, const float* __restrict__ bias2,
    const float* __restrict__ bias3, const float* __restrict__ res,
    void* __restrict__ Cout, void* __restrict__ C2, void* __restrict__ C3,
    int Mstride, int Mreal, int K, int ldw) {
  __shared__ __align__(16) ushort Ab[2][256 * 32];   // 16KB each buf
  __shared__ __align__(16) ushort Bb[2][256 * 32];   // total 64KB
  const int tid = threadIdx.x;
  const int l = tid & 63, w = tid >> 6;
  const int lr = l & 15, lg = l >> 4;
  const int wm = w >> 2, wn = w & 3;                 // 2 x 4 wave grid
  const int bn = blockIdx.x, bm = blockIdx.y;
  const int NS = K >> 5;                             // 32-K slices (even)

  // staging addresses: thread covers 2 A-slots + 2 B-slots of 16B
  // slot = i*512 + tid -> row = slot>>2, phys chunk c = slot&3 holds
  // logical chunk c ^ (row&3)  (inverse swizzle on the SOURCE).
  const int r0 = tid >> 2, c0 = (tid & 3) ^ (r0 & 3);
  const int r1 = (512 + tid) >> 2, c1 = (tid & 3) ^ (r1 & 3);
  const ushort* Ag0 = A + (size_t)(bn * 256 + r0) * K + c0 * 8;
  const ushort* Ag1 = A + (size_t)(bn * 256 + r1) * K + c1 * 8;
  const ushort* Wg0 = W + (size_t)(bm * 256 + r0) * ldw + c0 * 8;
  const ushort* Wg1 = W + (size_t)(bm * 256 + r1) * ldw + c1 * 8;
  const int dst0 = (w * 64) * 8;                     // wave-uniform LDS offsets
  const int dst1 = (512 + w * 64) * 8;

  // swizzled fragment read offsets (ushort units)
  const int swz = (lg ^ (lr & 3)) * 8;
  const int abase = (wm * 128 + lr) * 32 + swz;      // + mf*512
  const int bbase = (wn * 64 + lr) * 32 + swz;       // + nf*512

  f32x4 acc[8][4] = {};
  bf16x8 A0[8], A1[8], Bf[4];

  // prologue: stage slices 0,1; read A(0)
  GLL16(Ag0, &Ab[0][dst0]); GLL16(Ag1, &Ab[0][dst1]);
  GLL16(Wg0, &Bb[0][dst0]); GLL16(Wg1, &Bb[0][dst1]);
  GLL16(Ag0 + 32, &Ab[1][dst0]); GLL16(Ag1 + 32, &Ab[1][dst1]);
  GLL16(Wg0 + 32, &Bb[1][dst0]); GLL16(Wg1 + 32, &Bb[1][dst1]);
  asm volatile("s_waitcnt vmcnt(4)" ::: "memory");   // slice 0 landed
  __builtin_amdgcn_s_barrier();
  #pragma unroll
  for (int mf = 0; mf < 8; mf++)
    A0[mf] = *(const bf16x8*)&Ab[0][abase + mf * 512];
  asm volatile("s_waitcnt lgkmcnt(0)" ::: "memory");
  __builtin_amdgcn_sched_barrier(0);

#define GBODY(S, AC, AA)                                                      \
  {                                                                           \
    asm volatile("s_waitcnt vmcnt(0)" ::: "memory");  /* slice S(+1) landed */\
    __builtin_amdgcn_s_barrier();                                             \
    const ushort* bb_ = &Bb[(S) & 1][0];                                      \
    _Pragma("unroll")                                                         \
    for (int nf = 0; nf < 4; nf++)                                            \
      Bf[nf] = *(const bf16x8*)&bb_[bbase + nf * 512];                        \
    __builtin_amdgcn_sched_barrier(0);  /* pin B-reads before A-reads */      \
    if ((S) + 1 < NS) {                                                       \
      const ushort* ab_ = &Ab[((S) + 1) & 1][0];                              \
      _Pragma("unroll")                                                       \
      for (int mf = 0; mf < 8; mf++)                                          \
        AA[mf] = *(const bf16x8*)&ab_[abase + mf * 512];                      \
    }                                                                         \
    asm volatile("s_waitcnt lgkmcnt(8)" ::: "memory"); /* B(S) complete */    \
    __builtin_amdgcn_sched_barrier(0);                                        \
    if ((S) + 2 < NS) {                      /* stage S+2 over buffer S&1 */  \
      const int k0_ = ((S) + 2) * 32;                                         \
      GLL16(Ag0 + k0_, &Ab[(S) & 1][dst0]);                                   \
      GLL16(Ag1 + k0_, &Ab[(S) & 1][dst1]);                                   \
      GLL16(Wg0 + k0_, &Bb[(S) & 1][dst0]);                                   \
      GLL16(Wg1 + k0_, &Bb[(S) & 1][dst1]);                                   \
    }                                                                         \
    __builtin_amdgcn_s_setprio(1);                                            \
    _Pragma("unroll")                                                         \
    for (int mf = 0; mf < 8; mf++)                                            \
      _Pragma("unroll")                                                       \
      for (int nf = 0; nf < 4; nf++)                                          \
        acc[mf][nf] = __builtin_amdgcn_mfma_f32_16x16x32_bf16(                \
            AC[mf], Bf[nf], acc[mf][nf], 0, 0, 0);                            \
    __builtin_amdgcn_s_setprio(0);                                            \
    asm volatile("s_waitcnt lgkmcnt(0)" ::: "memory"); /* A(S+1) complete */  \
    __builtin_amdgcn_sched_barrier(0);                                        \
  }

  for (int t = 0; t < NS / 2; t++) {
    GBODY(2 * t, A0, A1)
    GBODY(2 * t + 1, A1, A0)
  }
#undef GBODY

  // ---------------- epilogue
  if (MODE == 4) {
    #pragma unroll
    for (int nf = 0; nf < 4; nf++) {
      const int c = bm * 256 + wn * 64 + nf * 16 + lr;
      if (c >= 3 * kD) continue;                      // M padded 3456->3584
      const int proj = c / kD;
      const int cl = c - proj * kD;
      const int jj = cl / 72, e = cl - jj * 72;
      const float bv = (proj == 0 ? bias : (proj == 1 ? bias2 : bias3))[cl];
      ushort* dp = (ushort*)(proj == 0 ? Cout : (proj == 1 ? C2 : C3));
      #pragma unroll
      for (int mf = 0; mf < 8; mf++) {
        #pragma unroll
        for (int j = 0; j < 4; j++) {
          const int r = bn * 256 + wm * 128 + mf * 16 + lg * 4 + j;
          float v = acc[mf][nf][j] + bv;
          if (proj == 0) v *= 0.11785113019775793f;   // 72^-0.5 folded into q
          const int b_ = r >> 10, t_ = r & 1023;
          const int h = t_ >> 6, u = t_ & 63;
          const int s2 = u * 16 + jj, bh = b_ * 16 + h;
          const size_t dst = (proj < 2) ? ((size_t)bh * 1024 + s2) * kEP + e
                                        : ((size_t)bh * kEV + e) * 1024 + s2;
          dp[dst] = f2bf(v);
        }
      }
    }
    return;
  }
  #pragma unroll
  for (int nf = 0; nf < 4; nf++) {
    const int c = bm * 256 + wn * 64 + nf * 16 + lr;
    if (c >= Mreal) continue;
    const float bv = bias[c];
    #pragma unroll
    for (int mf = 0; mf < 8; mf++) {
      #pragma unroll
      for (int j = 0; j < 4; j++) {
        const int r = bn * 256 + wm * 128 + mf * 16 + lg * 4 + j;
        float v = acc[mf][nf][j] + bv;
        if (GELU_) v = gelu_tanh(v);
        if (MODE == 0) {
          ((float*)Cout)[(size_t)r * Mstride + c] = v + res[(size_t)r * Mstride + c];
        } else {
          ((ushort*)Cout)[(size_t)r * Mstride + c] = f2bf(v);
        }
      }
    }
  }
}

// ------------------------------------------------------- MFMA flash attention
// (unchanged from round 6 — swapped QK^T, in-register P)
__global__ __launch_bounds__(256, 2) void attn_kernel(
    const ushort* __restrict__ qp, const ushort* __restrict__ kp,
    const ushort* __restrict__ vt, ushort* __restrict__ ob) {
  __shared__ __align__(16) ushort Kt[64 * 96];
  __shared__ __align__(16) ushort Vt[80 * 64];
  const int tid = threadIdx.x, l = tid & 63, w = tid >> 6;
  const int lr = l & 15, lg = l >> 4;
  const int qb = blockIdx.x, hh = blockIdx.y, bb = blockIdx.z;
  const int bh = bb * 16 + hh;
  const int s0 = qb * 256 + w * 64;
  bf16x8 qf[4][3];
  const ushort* qbase = qp + (size_t)bh * 1024 * kEP;
  #pragma unroll
  for (int qi = 0; qi < 4; qi++)
    #pragma unroll
    for (int ks = 0; ks < 3; ks++)
      qf[qi][ks] = *(const bf16x8*)(qbase + (size_t)(s0 + qi * 16 + lr) * kEP + ks * 32 + lg * 8);
  float mstate[4], lstate[4];
  #pragma unroll
  for (int i = 0; i < 4; i++) { mstate[i] = -1e30f; lstate[i] = 0.f; }
  f32x4 oacc[4][5] = {};
  const ushort* ktile0 = kp + (size_t)bh * 1024 * kEP;
  const ushort* vbase  = vt + (size_t)bh * kEV * 1024;
  const int srcA = lr + 32 * (lg & 1);
  const int srcB = srcA + 16;
  const int hi = lg >> 1;
  const int rmap = (lg << 4) + (lg << 2);

  for (int kt = 0; kt < 16; kt++) {
    __syncthreads();
    {
      const ushort* kg = ktile0 + (size_t)kt * 64 * kEP;
      #pragma unroll
      for (int i = 0; i < 3; i++) {
        const int is = w * 3 + i;
        GLL16(kg + is * 512 + l * 8, &Kt[is * 512]);
      }
    }
    {
      #pragma unroll
      for (int i = 0; i < 3; i++) {
        const int is = w + i * 4;
        if (is < 10) {
          const int e = is * 8 + (l >> 3);
          const int cg = (l & 7) ^ (e & 7);
          GLL16(vbase + (size_t)e * 1024 + kt * 64 + cg * 8, &Vt[is * 512]);
        }
      }
    }
    __syncthreads();
    f32x4 sacc[4][4];
    #pragma unroll
    for (int si = 0; si < 4; si++)
      #pragma unroll
      for (int qi = 0; qi < 4; qi++)
        sacc[si][qi] = (f32x4){0.f, 0.f, 0.f, 0.f};
    #pragma unroll
    for (int ks = 0; ks < 3; ks++) {
      bf16x8 kf[4];
      #pragma unroll
      for (int si = 0; si < 4; si++)
        kf[si] = *(const bf16x8*)&Kt[(si * 16 + lr) * 96 + ks * 32 + lg * 8];
      #pragma unroll
      for (int si = 0; si < 4; si++)
        #pragma unroll
        for (int qi = 0; qi < 4; qi++)
          sacc[si][qi] = __builtin_amdgcn_mfma_f32_16x16x32_bf16(kf[si], qf[qi][ks], sacc[si][qi], 0, 0, 0);
    }
    #pragma unroll
    for (int qi = 0; qi < 4; qi++) {
      float mx = sacc[0][qi][0];
      #pragma unroll
      for (int si = 0; si < 4; si++)
        #pragma unroll
        for (int j = 0; j < 4; j++) mx = fmaxf(mx, sacc[si][qi][j]);
      mx = fmaxf(mx, __shfl_xor(mx, 16));
      mx = fmaxf(mx, __shfl_xor(mx, 32));
      const float mo = mstate[qi], mn = fmaxf(mo, mx);
      float sum = 0.f;
      #pragma unroll
      for (int si = 0; si < 4; si++)
        #pragma unroll
        for (int j = 0; j < 4; j++) {
          const float p = __expf(sacc[si][qi][j] - mn);
          sacc[si][qi][j] = p;
          sum += p;
        }
      sum += __shfl_xor(sum, 16);
      sum += __shfl_xor(sum, 32);
      const float al = __expf(mo - mn);
      lstate[qi] = lstate[qi] * al + sum;
      mstate[qi] = mn;
      #pragma unroll
      for (int j = 0; j < 4; j++) {
        const float alj = __shfl(al, rmap + j);
        #pragma unroll
        for (int ei = 0; ei < 5; ei++) oacc[qi][ei][j] *= alj;
      }
      uint wlo[4], whi[4];
      #pragma unroll
      for (int si = 0; si < 4; si++) {
        wlo[si] = (uint)f2bf(sacc[si][qi][0]) | ((uint)f2bf(sacc[si][qi][1]) << 16);
        whi[si] = (uint)f2bf(sacc[si][qi][2]) | ((uint)f2bf(sacc[si][qi][3]) << 16);
      }
      uint Aq0[4], Aq1[4], Aq2[4], Aq3[4];
      #pragma unroll
      for (int si = 0; si < 4; si++) {
        Aq0[si] = (uint)__shfl((int)wlo[si], srcA);
        Aq1[si] = (uint)__shfl((int)whi[si], srcA);
        Aq2[si] = (uint)__shfl((int)wlo[si], srcB);
        Aq3[si] = (uint)__shfl((int)whi[si], srcB);
      }
      union U { uint u[4]; bf16x8 v; } p0, p1;
      p0.u[0] = hi ? Aq0[1] : Aq0[0];  p0.u[1] = hi ? Aq1[1] : Aq1[0];
      p0.u[2] = hi ? Aq2[1] : Aq2[0];  p0.u[3] = hi ? Aq3[1] : Aq3[0];
      p1.u[0] = hi ? Aq0[3] : Aq0[2];  p1.u[1] = hi ? Aq1[3] : Aq1[2];
      p1.u[2] = hi ? Aq2[3] : Aq2[2];  p1.u[3] = hi ? Aq3[3] : Aq3[2];
      #pragma unroll
      for (int ei = 0; ei < 5; ei++) {
        const int e = ei * 16 + lr;
        const int sw = e & 7;
        bf16x8 vb0 = *(const bf16x8*)&Vt[e * 64 + ((0 + lg) ^ sw) * 8];
        bf16x8 vb1 = *(const bf16x8*)&Vt[e * 64 + ((4 + lg) ^ sw) * 8];
        oacc[qi][ei] = __builtin_amdgcn_mfma_f32_16x16x32_bf16(p0.v, vb0, oacc[qi][ei], 0, 0, 0);
        oacc[qi][ei] = __builtin_amdgcn_mfma_f32_16x16x32_bf16(p1.v, vb1, oacc[qi][ei], 0, 0, 0);
      }
    }
  }
  #pragma unroll
  for (int qi = 0; qi < 4; qi++) {
    const float rli = 1.f / lstate[qi];
    float lij[4];
    #pragma unroll
    for (int j = 0; j < 4; j++) lij[j] = __shfl(rli, rmap + j);
    #pragma unroll
    for (int ei = 0; ei < 5; ei++) {
      const int e = ei * 16 + lr;
      if (e < 72) {
        #pragma unroll
        for (int j = 0; j < 4; j++) {
          const int s = s0 + qi * 16 + lg * 4 + j;
          ob[((size_t)bb * 1024 + s) * kD + hh * kHD + e] =
              f2bf(oacc[qi][ei][j] * lij[j]);
        }
      }
    }
  }
}

// ----------------------------------------------------------------- launch
extern "C" void kernel_launch(void* const* d_in, const int* in_sizes, int n_in,
                              void* d_out, int out_size, void* d_ws, size_t ws_size,
                              hipStream_t stream) {
  const float* x    = (const float*)d_in[0];
  const float* ln1w = (const float*)d_in[1];
  const float* ln1b = (const float*)d_in[2];
  const float* wq   = (const float*)d_in[3];
  const float* bq   = (const float*)d_in[4];
  const float* wk   = (const float*)d_in[5];
  const float* bk   = (const float*)d_in[6];
  const float* wv   = (const float*)d_in[7];
  const float* bv   = (const float*)d_in[8];
  const float* wo   = (const float*)d_in[9];
  const float* bo   = (const float*)d_in[10];
  const float* ln2w = (const float*)d_in[11];
  const float* ln2b = (const float*)d_in[12];
  const float* w1   = (const float*)d_in[13];
  const float* b1   = (const float*)d_in[14];
  const float* w2   = (const float*)d_in[15];
  const float* b2   = (const float*)d_in[16];
  float* out = (float*)d_out;

  // workspace layout (ushort units), span ~151.3 MiB (same as rounds 4-6)
  ushort* ws = (ushort*)d_ws;
  const size_t nD = (size_t)kNT * kD;                  // 9437184
  const size_t nQK = (size_t)kB * kNH * 1024 * kEP;    // 12582912
  const size_t nVT = (size_t)kB * kNH * kEV * 1024;    // 10485760
  ushort* hb  = ws;                 // LN1 out -> attn out (ob) -> LN2 out (h2b)
  ushort* qp  = hb + nD;
  ushort* kp  = qp + nQK;
  ushort* vt  = kp + nQK;
  ushort* wqb = vt + nVT;           // wq/wk/wv contiguous = merged W [3456][1152]
  ushort* wkb = wqb + (size_t)kD * kD;
  ushort* wvb = wkb + (size_t)kD * kD;
  ushort* wob = wvb + (size_t)kD * kD;
  ushort* w1b = wob + (size_t)kD * kD;     // [4352][1152] (pad rows zeroed)
  ushort* w2b = w1b + (size_t)kFP * kD;    // [1152][4352] (pad cols zeroed)
  float*  x1  = (float*)(w2b + (size_t)kD * kFP);
  float*  b1b = x1 + nD;
  ushort* ob  = hb;
  ushort* h2b = hb;                 // LN2 out reuses hb (ob dead after o-proj)
  ushort* fb  = qp;                 // [8192][4352] bf16 = qp+kp+vt exactly

  const dim3 blk(256), blkg(512);
  const dim3 gqkv(32, 14);          // 256-tiles: N=8192/256, M=3584/256
  const dim3 go(32, 5);             // M padded 1152->1280
  const dim3 gw1(32, 17);           // M=4352/256
  const dim3 ga(4, 16, 8);

  // weight/bias conversion (per-launch; inputs restored each call)
  const int nDD4 = kD * kD / 4;
  cvt4_kernel<<<(nDD4 + 255) / 256, blk, 0, stream>>>(wq, wqb, nDD4);
  cvt4_kernel<<<(nDD4 + 255) / 256, blk, 0, stream>>>(wk, wkb, nDD4);
  cvt4_kernel<<<(nDD4 + 255) / 256, blk, 0, stream>>>(wv, wvb, nDD4);
  cvt4_kernel<<<(nDD4 + 255) / 256, blk, 0, stream>>>(wo, wob, nDD4);
  const int nW14 = kF * kD / 4;
  cvt4_kernel<<<(nW14 + 255) / 256, blk, 0, stream>>>(w1, w1b, nW14);
  cvtw2_kernel<<<(kD * (kFP / 4) + 255) / 256, blk, 0, stream>>>(w2, w2b);
  b1pad_kernel<<<(kFP + (kFP - kF) * kD + 255) / 256, blk, 0, stream>>>(b1, b1b, w1b);
  zfill_kernel<<<16384, blk, 0, stream>>>(kp, vt);

  ln_kernel<<<kNT, blk, 0, stream>>>(x, ln1w, ln1b, hb);
  gemm256<4, 0><<<gqkv, blkg, 0, stream>>>(hb, wqb, bq, bk, bv, nullptr,
                                           qp, kp, vt, 0, 3456, kD, kD);
  attn_kernel<<<ga, blk, 0, stream>>>(qp, kp, vt, ob);
  gemm256<0, 0><<<go, blkg, 0, stream>>>(ob, wob, bo, nullptr, nullptr, x,
                                         x1, nullptr, nullptr, kD, kD, kD, kD);
  ln_kernel<<<kNT, blk, 0, stream>>>(x1, ln2w, ln2b, h2b);
  gemm256<1, 1><<<gw1, blkg, 0, stream>>>(h2b, w1b, b1b, nullptr, nullptr, nullptr,
                                          fb, nullptr, nullptr, kFP, kFP, kD, kD);
  gemm256<0, 0><<<go, blkg, 0, stream>>>(fb, w2b, b2, nullptr, nullptr, x1,
                                         out, nullptr, nullptr, kD, kD, kFP, kFP);
}